// Round 1
// baseline (1827.640 us; speedup 1.0000x reference)
//
#include <hip/hip_runtime.h>
#include <stdint.h>

typedef __bf16 bf16;
typedef __bf16 bf16x4 __attribute__((ext_vector_type(4)));
typedef __bf16 bf16x8 __attribute__((ext_vector_type(8)));
typedef float  f32x4  __attribute__((ext_vector_type(4)));

#define T_TOK 8192
#define D_DIM 2048
#define F_DIM 3584
#define E_NUM 8
#define RTOT  16384   // T_TOK * top_k

// async global->LDS, 16B per lane, lds ptr must be wave-uniform base (HW adds lane*16)
__device__ __forceinline__ void g2l16(const bf16* g, bf16* lds) {
  __builtin_amdgcn_global_load_lds((const __attribute__((address_space(1))) void*)g,
                                   (__attribute__((address_space(3))) void*)lds,
                                   16, 0, 0);
}

// ---------------- utility kernels ----------------

__global__ __launch_bounds__(256) void zero_f32_kernel(float* __restrict__ p, size_t n4) {
  // n4 = number of float4 groups
  size_t i = (size_t)blockIdx.x * blockDim.x + threadIdx.x;
  size_t stride = (size_t)gridDim.x * blockDim.x;
  float4 z = make_float4(0.f, 0.f, 0.f, 0.f);
  for (; i < n4; i += stride) ((float4*)p)[i] = z;
}

__global__ void zero_meta_kernel(int* __restrict__ counts, int* __restrict__ fill) {
  if (threadIdx.x < E_NUM) { counts[threadIdx.x] = 0; fill[threadIdx.x] = 0; }
}

__global__ __launch_bounds__(256) void cvt_bf16_kernel(const float* __restrict__ src,
                                                       bf16* __restrict__ dst, size_t n) {
  size_t i = ((size_t)blockIdx.x * blockDim.x + threadIdx.x) * 4;
  size_t stride = (size_t)gridDim.x * blockDim.x * 4;
  for (; i < n; i += stride) {
    float4 v = *(const float4*)(src + i);
    bf16x4 o;
    o[0] = (bf16)v.x; o[1] = (bf16)v.y; o[2] = (bf16)v.z; o[3] = (bf16)v.w;
    *(bf16x4*)(dst + i) = o;
  }
}

// ---------------- router: logits, top-2, weights ----------------

__global__ __launch_bounds__(256) void router_kernel(const float* __restrict__ x,
                                                     const float* __restrict__ gw,
                                                     int* __restrict__ tok_e,
                                                     float* __restrict__ tok_w) {
  int wave = threadIdx.x >> 6;
  int lane = threadIdx.x & 63;
  int t = blockIdx.x * 4 + wave;
  const float* xr = x + (size_t)t * D_DIM;
  float acc[E_NUM];
#pragma unroll
  for (int e = 0; e < E_NUM; ++e) acc[e] = 0.f;
  for (int k = lane; k < D_DIM; k += 64) {
    float xv = xr[k];
#pragma unroll
    for (int e = 0; e < E_NUM; ++e) acc[e] += xv * gw[e * D_DIM + k];
  }
#pragma unroll
  for (int e = 0; e < E_NUM; ++e) {
    float v = acc[e];
#pragma unroll
    for (int off = 32; off > 0; off >>= 1) v += __shfl_xor(v, off, 64);
    acc[e] = v;
  }
  if (lane == 0) {
    int e0 = 0; float l0 = acc[0];
#pragma unroll
    for (int e = 1; e < E_NUM; ++e) if (acc[e] > l0) { l0 = acc[e]; e0 = e; }
    int e1 = -1; float l1 = -3.0e38f;
#pragma unroll
    for (int e = 0; e < E_NUM; ++e) if (e != e0 && acc[e] > l1) { l1 = acc[e]; e1 = e; }
    float w0 = 1.f / (1.f + expf(l1 - l0));   // softmax over {l0,l1}, renormalized
    float w1 = 1.f - w0;
    tok_e[2 * t] = e0; tok_e[2 * t + 1] = e1;
    tok_w[2 * t] = w0; tok_w[2 * t + 1] = w1;
  }
}

// ---------------- count / scan / scatter ----------------

__global__ __launch_bounds__(256) void count_kernel(const int* __restrict__ tok_e,
                                                    int* __restrict__ counts) {
  __shared__ int c[E_NUM];
  if (threadIdx.x < E_NUM) c[threadIdx.x] = 0;
  __syncthreads();
  int t = blockIdx.x * 256 + threadIdx.x;
  atomicAdd(&c[tok_e[2 * t]], 1);
  atomicAdd(&c[tok_e[2 * t + 1]], 1);
  __syncthreads();
  if (threadIdx.x < E_NUM) atomicAdd(&counts[threadIdx.x], c[threadIdx.x]);
}

__global__ void scan_kernel(const int* __restrict__ counts, int* __restrict__ offsets,
                            int* __restrict__ fill) {
  if (threadIdx.x == 0) {
    int s = 0;
    for (int e = 0; e < E_NUM; ++e) { offsets[e] = s; s += counts[e]; fill[e] = 0; }
    offsets[E_NUM] = s;
  }
}

__global__ __launch_bounds__(256) void scatter_kernel(const int* __restrict__ tok_e,
                                                      const float* __restrict__ tok_w,
                                                      const int* __restrict__ offsets,
                                                      int* __restrict__ fill,
                                                      int* __restrict__ map,
                                                      float* __restrict__ wbuf) {
  __shared__ int c[E_NUM], base[E_NUM];
  if (threadIdx.x < E_NUM) c[threadIdx.x] = 0;
  __syncthreads();
  int t = blockIdx.x * 256 + threadIdx.x;
  int e0 = tok_e[2 * t], e1 = tok_e[2 * t + 1];
  int r0 = atomicAdd(&c[e0], 1);
  int r1 = atomicAdd(&c[e1], 1);
  __syncthreads();
  if (threadIdx.x < E_NUM) base[threadIdx.x] = atomicAdd(&fill[threadIdx.x], c[threadIdx.x]);
  __syncthreads();
  int p0 = offsets[e0] + base[e0] + r0;
  int p1 = offsets[e1] + base[e1] + r1;
  map[p0] = t; wbuf[p0] = tok_w[2 * t];
  map[p1] = t; wbuf[p1] = tok_w[2 * t + 1];
}

// ---------------- gather x rows -> bf16 (segment order) ----------------

__global__ __launch_bounds__(256) void gather_kernel(const float* __restrict__ x,
                                                     const int* __restrict__ map,
                                                     bf16* __restrict__ Xg) {
  int row = blockIdx.x;
  int t = map[row];
  const float* src = x + (size_t)t * D_DIM;
  bf16* dst = Xg + (size_t)row * D_DIM;
  int k = threadIdx.x * 8;
  float4 a = *(const float4*)(src + k);
  float4 b = *(const float4*)(src + k + 4);
  bf16x8 o;
  o[0] = (bf16)a.x; o[1] = (bf16)a.y; o[2] = (bf16)a.z; o[3] = (bf16)a.w;
  o[4] = (bf16)b.x; o[5] = (bf16)b.y; o[6] = (bf16)b.z; o[7] = (bf16)b.w;
  *(bf16x8*)(dst + k) = o;
}

// ---------------- GEMM1: Xg @ wv1[e]^T, fused silu(gate)*up -> act (bf16) ----------------
// 128x128 tile (gate cols + matching up cols), BK=32, 4 waves 2x2, dual accumulators.

__global__ __launch_bounds__(256, 2) void gemm1_kernel(const bf16* __restrict__ Xg,
                                                       const bf16* __restrict__ Wv1b,
                                                       bf16* __restrict__ act,
                                                       const int* __restrict__ counts,
                                                       const int* __restrict__ offsets) {
  const int e = blockIdx.z;
  const int n_e = counts[e];
  const int mt = blockIdx.y;
  if (mt * 128 >= n_e) return;
  const int seg = offsets[e];
  const int rmax = n_e - mt * 128;          // valid local rows in this tile (>=1)
  const int n0 = blockIdx.x * 128;

  __shared__ __align__(16) bf16 As[128 * 32];
  __shared__ __align__(16) bf16 Bg[128 * 32];
  __shared__ __align__(16) bf16 Bu[128 * 32];

  const int t = threadIdx.x;
  const int kq = t & 3;          // 16B chunk within a 32-elem row
  const int r0 = t >> 2;         // staging row, issue 0
  const int lane = t & 63;
  const int w = t >> 6;
  const int wm = w >> 1, wn = w & 1;
  const int quad = lane >> 4, l16 = lane & 15;
  const int wbase = w << 9;      // wave-uniform LDS elem base (w*64 lanes * 8 elems)

  int ra0 = r0;      if (ra0 > rmax - 1) ra0 = rmax - 1;   // clamp ragged tail (garbage rows masked at store)
  int ra1 = r0 + 64; if (ra1 > rmax - 1) ra1 = rmax - 1;
  const bf16* gA0 = Xg + (size_t)(seg + mt * 128 + ra0) * D_DIM + (kq << 3);
  const bf16* gA1 = Xg + (size_t)(seg + mt * 128 + ra1) * D_DIM + (kq << 3);
  const bf16* We  = Wv1b + (size_t)e * (2 * (size_t)F_DIM) * D_DIM;
  const bf16* gG0 = We + (size_t)(n0 + r0) * D_DIM + (kq << 3);
  const bf16* gG1 = We + (size_t)(n0 + r0 + 64) * D_DIM + (kq << 3);
  const bf16* gU0 = gG0 + (size_t)F_DIM * D_DIM;
  const bf16* gU1 = gG1 + (size_t)F_DIM * D_DIM;

  f32x4 accG[4][4], accU[4][4];
#pragma unroll
  for (int i = 0; i < 4; ++i)
#pragma unroll
    for (int j = 0; j < 4; ++j) {
      accG[i][j] = f32x4{0.f, 0.f, 0.f, 0.f};
      accU[i][j] = f32x4{0.f, 0.f, 0.f, 0.f};
    }

  for (int kt = 0; kt < D_DIM / 32; ++kt) {
    g2l16(gA0, As + wbase);
    g2l16(gA1, As + 2048 + wbase);
    g2l16(gG0, Bg + wbase);
    g2l16(gG1, Bg + 2048 + wbase);
    g2l16(gU0, Bu + wbase);
    g2l16(gU1, Bu + 2048 + wbase);
    __syncthreads();

    bf16x8 af[4], bgf[4], buf_[4];
#pragma unroll
    for (int mi = 0; mi < 4; ++mi)
      af[mi] = *(const bf16x8*)(As + (wm * 64 + mi * 16 + l16) * 32 + (quad << 3));
#pragma unroll
    for (int ni = 0; ni < 4; ++ni) {
      bgf[ni]  = *(const bf16x8*)(Bg + (wn * 64 + ni * 16 + l16) * 32 + (quad << 3));
      buf_[ni] = *(const bf16x8*)(Bu + (wn * 64 + ni * 16 + l16) * 32 + (quad << 3));
    }
#pragma unroll
    for (int mi = 0; mi < 4; ++mi)
#pragma unroll
      for (int ni = 0; ni < 4; ++ni) {
        accG[mi][ni] = __builtin_amdgcn_mfma_f32_16x16x32_bf16(af[mi], bgf[ni], accG[mi][ni], 0, 0, 0);
        accU[mi][ni] = __builtin_amdgcn_mfma_f32_16x16x32_bf16(af[mi], buf_[ni], accU[mi][ni], 0, 0, 0);
      }
    __syncthreads();
    gA0 += 32; gA1 += 32; gG0 += 32; gG1 += 32; gU0 += 32; gU1 += 32;
  }

  // epilogue: silu(gate)*up -> bf16, C/D layout col=lane&15, row=quad*4+reg
#pragma unroll
  for (int mi = 0; mi < 4; ++mi) {
#pragma unroll
    for (int j = 0; j < 4; ++j) {
      int r = wm * 64 + mi * 16 + quad * 4 + j;
      if (r < rmax) {
        bf16* dst = act + (size_t)(seg + mt * 128 + r) * F_DIM + n0 + wn * 64 + l16;
#pragma unroll
        for (int ni = 0; ni < 4; ++ni) {
          float g = accG[mi][ni][j];
          float u = accU[mi][ni][j];
          float s = g / (1.f + __expf(-g));
          dst[ni * 16] = (bf16)(s * u);
        }
      }
    }
  }
}

// ---------------- GEMM2: act @ w2[e]^T, scaled atomic scatter-add to out ----------------

__global__ __launch_bounds__(256, 2) void gemm2_kernel(const bf16* __restrict__ act,
                                                       const bf16* __restrict__ W2b,
                                                       float* __restrict__ out,
                                                       const int* __restrict__ counts,
                                                       const int* __restrict__ offsets,
                                                       const int* __restrict__ map,
                                                       const float* __restrict__ wbuf) {
  const int e = blockIdx.z;
  const int n_e = counts[e];
  const int mt = blockIdx.y;
  if (mt * 128 >= n_e) return;
  const int seg = offsets[e];
  const int rmax = n_e - mt * 128;
  const int n0 = blockIdx.x * 128;

  __shared__ __align__(16) bf16 As[128 * 32];
  __shared__ __align__(16) bf16 Bs[128 * 32];
  __shared__ int   smap[128];
  __shared__ float sw[128];

  const int t = threadIdx.x;
  if (t < 128) {
    int rr = t; if (rr > rmax - 1) rr = rmax - 1;
    smap[t] = map[seg + mt * 128 + rr];
    sw[t]   = wbuf[seg + mt * 128 + rr];
  }

  const int kq = t & 3;
  const int r0 = t >> 2;
  const int lane = t & 63;
  const int w = t >> 6;
  const int wm = w >> 1, wn = w & 1;
  const int quad = lane >> 4, l16 = lane & 15;
  const int wbase = w << 9;

  int ra0 = r0;      if (ra0 > rmax - 1) ra0 = rmax - 1;
  int ra1 = r0 + 64; if (ra1 > rmax - 1) ra1 = rmax - 1;
  const bf16* gA0 = act + (size_t)(seg + mt * 128 + ra0) * F_DIM + (kq << 3);
  const bf16* gA1 = act + (size_t)(seg + mt * 128 + ra1) * F_DIM + (kq << 3);
  const bf16* W2e = W2b + (size_t)e * D_DIM * (size_t)F_DIM;
  const bf16* gB0 = W2e + (size_t)(n0 + r0) * F_DIM + (kq << 3);
  const bf16* gB1 = W2e + (size_t)(n0 + r0 + 64) * F_DIM + (kq << 3);

  f32x4 acc[4][4];
#pragma unroll
  for (int i = 0; i < 4; ++i)
#pragma unroll
    for (int j = 0; j < 4; ++j) acc[i][j] = f32x4{0.f, 0.f, 0.f, 0.f};

  for (int kt = 0; kt < F_DIM / 32; ++kt) {
    g2l16(gA0, As + wbase);
    g2l16(gA1, As + 2048 + wbase);
    g2l16(gB0, Bs + wbase);
    g2l16(gB1, Bs + 2048 + wbase);
    __syncthreads();

    bf16x8 af[4], bf[4];
#pragma unroll
    for (int mi = 0; mi < 4; ++mi)
      af[mi] = *(const bf16x8*)(As + (wm * 64 + mi * 16 + l16) * 32 + (quad << 3));
#pragma unroll
    for (int ni = 0; ni < 4; ++ni)
      bf[ni] = *(const bf16x8*)(Bs + (wn * 64 + ni * 16 + l16) * 32 + (quad << 3));
#pragma unroll
    for (int mi = 0; mi < 4; ++mi)
#pragma unroll
      for (int ni = 0; ni < 4; ++ni)
        acc[mi][ni] = __builtin_amdgcn_mfma_f32_16x16x32_bf16(af[mi], bf[ni], acc[mi][ni], 0, 0, 0);
    __syncthreads();
    gA0 += 32; gA1 += 32; gB0 += 32; gB1 += 32;
  }

#pragma unroll
  for (int mi = 0; mi < 4; ++mi) {
#pragma unroll
    for (int j = 0; j < 4; ++j) {
      int r = wm * 64 + mi * 16 + quad * 4 + j;
      if (r < rmax) {
        int tok = smap[r];
        float wgt = sw[r];
        float* dst = out + (size_t)tok * D_DIM + n0 + wn * 64 + l16;
#pragma unroll
        for (int ni = 0; ni < 4; ++ni)
          atomicAdd(dst + ni * 16, wgt * acc[mi][ni][j]);
      }
    }
  }
}

// ---------------- launch ----------------

extern "C" void kernel_launch(void* const* d_in, const int* in_sizes, int n_in,
                              void* d_out, int out_size, void* d_ws, size_t ws_size,
                              hipStream_t stream) {
  const float* x   = (const float*)d_in[0];
  const float* gw  = (const float*)d_in[1];
  const float* wv1 = (const float*)d_in[2];
  const float* w2  = (const float*)d_in[3];
  float* out = (float*)d_out;

  const size_t WV1_N = (size_t)E_NUM * 2 * F_DIM * D_DIM;  // 117,440,512
  const size_t W2_N  = (size_t)E_NUM * D_DIM * F_DIM;      //  58,720,256

  char* ws = (char*)d_ws;
  size_t off = 0;
  auto alloc = [&](size_t bytes) -> char* {
    char* p = ws + off;
    off += (bytes + 255) & ~(size_t)255;
    return p;
  };
  bf16*  wv1b   = (bf16*)alloc(WV1_N * 2);
  bf16*  w2b    = (bf16*)alloc(W2_N * 2);
  bf16*  Xg     = (bf16*)alloc((size_t)RTOT * D_DIM * 2);
  bf16*  act    = (bf16*)alloc((size_t)RTOT * F_DIM * 2);
  int*   tok_e  = (int*)alloc(RTOT * 4);
  float* tok_w  = (float*)alloc(RTOT * 4);
  int*   map    = (int*)alloc(RTOT * 4);
  float* wbuf   = (float*)alloc(RTOT * 4);
  int*   counts = (int*)alloc(256);
  int*   offs   = (int*)alloc(256);
  int*   fill   = (int*)alloc(256);
  if (off > ws_size) return;  // workspace too small; fail loudly via wrong output

  zero_f32_kernel<<<2048, 256, 0, stream>>>(out, (size_t)out_size / 4);
  zero_meta_kernel<<<1, 64, 0, stream>>>(counts, fill);
  cvt_bf16_kernel<<<4096, 256, 0, stream>>>(wv1, wv1b, WV1_N);
  cvt_bf16_kernel<<<4096, 256, 0, stream>>>(w2, w2b, W2_N);
  router_kernel<<<T_TOK / 4, 256, 0, stream>>>(x, gw, tok_e, tok_w);
  count_kernel<<<T_TOK / 256, 256, 0, stream>>>(tok_e, counts);
  scan_kernel<<<1, 64, 0, stream>>>(counts, offs, fill);
  scatter_kernel<<<T_TOK / 256, 256, 0, stream>>>(tok_e, tok_w, offs, fill, map, wbuf);
  gather_kernel<<<RTOT, 256, 0, stream>>>(x, map, Xg);
  gemm1_kernel<<<dim3(F_DIM / 128, 64, E_NUM), 256, 0, stream>>>(Xg, wv1b, act, counts, offs);
  gemm2_kernel<<<dim3(D_DIM / 128, 64, E_NUM), 256, 0, stream>>>(act, w2b, out, counts, offs, map, wbuf);
}

// Round 2
// 1808.165 us; speedup vs baseline: 1.0108x; 1.0108x over previous
//
#include <hip/hip_runtime.h>
#include <stdint.h>

typedef __bf16 bf16;
typedef __bf16 bf16x4 __attribute__((ext_vector_type(4)));
typedef __bf16 bf16x8 __attribute__((ext_vector_type(8)));
typedef float  f32x4  __attribute__((ext_vector_type(4)));

#define T_TOK 8192
#define D_DIM 2048
#define F_DIM 3584
#define E_NUM 8
#define RTOT  16384   // T_TOK * top_k

// XOR-swizzled LDS slot for (row, 16B-chunk q). Slot stride = 8 elems (16B).
// Bank-start over 8 consecutive rows covers all 32 banks -> conflict-free b128.
#define SLOT_OFF(r, q) ((((r) << 2) + ((q) ^ (((r) >> 1) & 3))) << 3)

// async global->LDS, 16B per lane, lds ptr must be wave-uniform base (HW adds lane*16)
__device__ __forceinline__ void g2l16(const bf16* g, bf16* lds) {
  __builtin_amdgcn_global_load_lds((const __attribute__((address_space(1))) void*)g,
                                   (__attribute__((address_space(3))) void*)lds,
                                   16, 0, 0);
}

// ---------------- utility kernels ----------------

__global__ __launch_bounds__(256) void zero_f32_kernel(float* __restrict__ p, size_t n4) {
  size_t i = (size_t)blockIdx.x * blockDim.x + threadIdx.x;
  size_t stride = (size_t)gridDim.x * blockDim.x;
  float4 z = make_float4(0.f, 0.f, 0.f, 0.f);
  for (; i < n4; i += stride) ((float4*)p)[i] = z;
}

__global__ void zero_meta_kernel(int* __restrict__ counts, int* __restrict__ fill) {
  if (threadIdx.x < E_NUM) { counts[threadIdx.x] = 0; fill[threadIdx.x] = 0; }
}

__global__ __launch_bounds__(256) void cvt_bf16_kernel(const float* __restrict__ src,
                                                       bf16* __restrict__ dst, size_t n) {
  size_t i = ((size_t)blockIdx.x * blockDim.x + threadIdx.x) * 4;
  size_t stride = (size_t)gridDim.x * blockDim.x * 4;
  for (; i < n; i += stride) {
    float4 v = *(const float4*)(src + i);
    bf16x4 o;
    o[0] = (bf16)v.x; o[1] = (bf16)v.y; o[2] = (bf16)v.z; o[3] = (bf16)v.w;
    *(bf16x4*)(dst + i) = o;
  }
}

// ---------------- router: logits, top-2, weights ----------------

__global__ __launch_bounds__(256) void router_kernel(const float* __restrict__ x,
                                                     const float* __restrict__ gw,
                                                     int* __restrict__ tok_e,
                                                     float* __restrict__ tok_w) {
  int wave = threadIdx.x >> 6;
  int lane = threadIdx.x & 63;
  int t = blockIdx.x * 4 + wave;
  const float* xr = x + (size_t)t * D_DIM;
  float acc[E_NUM];
#pragma unroll
  for (int e = 0; e < E_NUM; ++e) acc[e] = 0.f;
  for (int k = lane; k < D_DIM; k += 64) {
    float xv = xr[k];
#pragma unroll
    for (int e = 0; e < E_NUM; ++e) acc[e] += xv * gw[e * D_DIM + k];
  }
#pragma unroll
  for (int e = 0; e < E_NUM; ++e) {
    float v = acc[e];
#pragma unroll
    for (int off = 32; off > 0; off >>= 1) v += __shfl_xor(v, off, 64);
    acc[e] = v;
  }
  if (lane == 0) {
    int e0 = 0; float l0 = acc[0];
#pragma unroll
    for (int e = 1; e < E_NUM; ++e) if (acc[e] > l0) { l0 = acc[e]; e0 = e; }
    int e1 = -1; float l1 = -3.0e38f;
#pragma unroll
    for (int e = 0; e < E_NUM; ++e) if (e != e0 && acc[e] > l1) { l1 = acc[e]; e1 = e; }
    float w0 = 1.f / (1.f + expf(l1 - l0));   // softmax over {l0,l1}, renormalized
    float w1 = 1.f - w0;
    tok_e[2 * t] = e0; tok_e[2 * t + 1] = e1;
    tok_w[2 * t] = w0; tok_w[2 * t + 1] = w1;
  }
}

// ---------------- count / scan / scatter ----------------

__global__ __launch_bounds__(256) void count_kernel(const int* __restrict__ tok_e,
                                                    int* __restrict__ counts) {
  __shared__ int c[E_NUM];
  if (threadIdx.x < E_NUM) c[threadIdx.x] = 0;
  __syncthreads();
  int t = blockIdx.x * 256 + threadIdx.x;
  atomicAdd(&c[tok_e[2 * t]], 1);
  atomicAdd(&c[tok_e[2 * t + 1]], 1);
  __syncthreads();
  if (threadIdx.x < E_NUM) atomicAdd(&counts[threadIdx.x], c[threadIdx.x]);
}

__global__ void scan_kernel(const int* __restrict__ counts, int* __restrict__ offsets,
                            int* __restrict__ fill) {
  if (threadIdx.x == 0) {
    int s = 0;
    for (int e = 0; e < E_NUM; ++e) { offsets[e] = s; s += counts[e]; fill[e] = 0; }
    offsets[E_NUM] = s;
  }
}

__global__ __launch_bounds__(256) void scatter_kernel(const int* __restrict__ tok_e,
                                                      const float* __restrict__ tok_w,
                                                      const int* __restrict__ offsets,
                                                      int* __restrict__ fill,
                                                      int* __restrict__ map,
                                                      float* __restrict__ wbuf) {
  __shared__ int c[E_NUM], base[E_NUM];
  if (threadIdx.x < E_NUM) c[threadIdx.x] = 0;
  __syncthreads();
  int t = blockIdx.x * 256 + threadIdx.x;
  int e0 = tok_e[2 * t], e1 = tok_e[2 * t + 1];
  int r0 = atomicAdd(&c[e0], 1);
  int r1 = atomicAdd(&c[e1], 1);
  __syncthreads();
  if (threadIdx.x < E_NUM) base[threadIdx.x] = atomicAdd(&fill[threadIdx.x], c[threadIdx.x]);
  __syncthreads();
  int p0 = offsets[e0] + base[e0] + r0;
  int p1 = offsets[e1] + base[e1] + r1;
  map[p0] = t; wbuf[p0] = tok_w[2 * t];
  map[p1] = t; wbuf[p1] = tok_w[2 * t + 1];
}

// ---------------- gather x rows -> bf16 (segment order) ----------------

__global__ __launch_bounds__(256) void gather_kernel(const float* __restrict__ x,
                                                     const int* __restrict__ map,
                                                     bf16* __restrict__ Xg) {
  int row = blockIdx.x;
  int t = map[row];
  const float* src = x + (size_t)t * D_DIM;
  bf16* dst = Xg + (size_t)row * D_DIM;
  int k = threadIdx.x * 8;
  float4 a = *(const float4*)(src + k);
  float4 b = *(const float4*)(src + k + 4);
  bf16x8 o;
  o[0] = (bf16)a.x; o[1] = (bf16)a.y; o[2] = (bf16)a.z; o[3] = (bf16)a.w;
  o[4] = (bf16)b.x; o[5] = (bf16)b.y; o[6] = (bf16)b.z; o[7] = (bf16)b.w;
  *(bf16x8*)(dst + k) = o;
}

// ---------------- GEMM1: Xg @ wv1[e]^T, fused silu(gate)*up -> act (bf16) ----------------
// 128x128 tile (gate cols + matching up cols), BK=32, 4 waves 2x2, dual accumulators.
// LDS layout XOR-swizzled (SLOT_OFF) for conflict-free ds_read_b128.

__global__ __launch_bounds__(256, 2) void gemm1_kernel(const bf16* __restrict__ Xg,
                                                       const bf16* __restrict__ Wv1b,
                                                       bf16* __restrict__ act,
                                                       const int* __restrict__ counts,
                                                       const int* __restrict__ offsets) {
  const int e = blockIdx.z;
  const int n_e = counts[e];
  const int mt = blockIdx.y;
  if (mt * 128 >= n_e) return;
  const int seg = offsets[e];
  const int rmax = n_e - mt * 128;          // valid local rows in this tile (>=1)
  const int n0 = blockIdx.x * 128;

  __shared__ __align__(16) bf16 As[128 * 32];
  __shared__ __align__(16) bf16 Bg[128 * 32];
  __shared__ __align__(16) bf16 Bu[128 * 32];

  const int t = threadIdx.x;
  const int r0 = t >> 2;                      // staging row within half
  const int kq = (t & 3) ^ ((t >> 3) & 3);    // swizzled 16B chunk for staging
  const int lane = t & 63;
  const int w = t >> 6;
  const int wm = w >> 1, wn = w & 1;
  const int quad = lane >> 4, l16 = lane & 15;
  const int wbase = w << 9;      // wave-uniform LDS elem base (w*64 lanes * 8 elems)

  int ra0 = r0;      if (ra0 > rmax - 1) ra0 = rmax - 1;   // clamp ragged tail
  int ra1 = r0 + 64; if (ra1 > rmax - 1) ra1 = rmax - 1;
  const bf16* gA0 = Xg + (size_t)(seg + mt * 128 + ra0) * D_DIM + (kq << 3);
  const bf16* gA1 = Xg + (size_t)(seg + mt * 128 + ra1) * D_DIM + (kq << 3);
  const bf16* We  = Wv1b + (size_t)e * (2 * (size_t)F_DIM) * D_DIM;
  const bf16* gG0 = We + (size_t)(n0 + r0) * D_DIM + (kq << 3);
  const bf16* gG1 = We + (size_t)(n0 + r0 + 64) * D_DIM + (kq << 3);
  const bf16* gU0 = gG0 + (size_t)F_DIM * D_DIM;
  const bf16* gU1 = gG1 + (size_t)F_DIM * D_DIM;

  f32x4 accG[4][4], accU[4][4];
#pragma unroll
  for (int i = 0; i < 4; ++i)
#pragma unroll
    for (int j = 0; j < 4; ++j) {
      accG[i][j] = f32x4{0.f, 0.f, 0.f, 0.f};
      accU[i][j] = f32x4{0.f, 0.f, 0.f, 0.f};
    }

  for (int kt = 0; kt < D_DIM / 32; ++kt) {
    g2l16(gA0, As + wbase);
    g2l16(gA1, As + 2048 + wbase);
    g2l16(gG0, Bg + wbase);
    g2l16(gG1, Bg + 2048 + wbase);
    g2l16(gU0, Bu + wbase);
    g2l16(gU1, Bu + 2048 + wbase);
    __syncthreads();

    bf16x8 af[4], bgf[4], buf_[4];
#pragma unroll
    for (int mi = 0; mi < 4; ++mi)
      af[mi] = *(const bf16x8*)(As + SLOT_OFF(wm * 64 + mi * 16 + l16, quad));
#pragma unroll
    for (int ni = 0; ni < 4; ++ni) {
      bgf[ni]  = *(const bf16x8*)(Bg + SLOT_OFF(wn * 64 + ni * 16 + l16, quad));
      buf_[ni] = *(const bf16x8*)(Bu + SLOT_OFF(wn * 64 + ni * 16 + l16, quad));
    }
#pragma unroll
    for (int mi = 0; mi < 4; ++mi)
#pragma unroll
      for (int ni = 0; ni < 4; ++ni) {
        accG[mi][ni] = __builtin_amdgcn_mfma_f32_16x16x32_bf16(af[mi], bgf[ni], accG[mi][ni], 0, 0, 0);
        accU[mi][ni] = __builtin_amdgcn_mfma_f32_16x16x32_bf16(af[mi], buf_[ni], accU[mi][ni], 0, 0, 0);
      }
    __syncthreads();
    gA0 += 32; gA1 += 32; gG0 += 32; gG1 += 32; gU0 += 32; gU1 += 32;
  }

  // epilogue: silu(gate)*up -> bf16, C/D layout col=lane&15, row=quad*4+reg
#pragma unroll
  for (int mi = 0; mi < 4; ++mi) {
#pragma unroll
    for (int j = 0; j < 4; ++j) {
      int r = wm * 64 + mi * 16 + quad * 4 + j;
      if (r < rmax) {
        bf16* dst = act + (size_t)(seg + mt * 128 + r) * F_DIM + n0 + wn * 64 + l16;
#pragma unroll
        for (int ni = 0; ni < 4; ++ni) {
          float g = accG[mi][ni][j];
          float u = accU[mi][ni][j];
          float s = g / (1.f + __expf(-g));
          dst[ni * 16] = (bf16)(s * u);
        }
      }
    }
  }
}

// ---------------- GEMM2: act @ w2[e]^T, scaled atomic scatter-add to out ----------------

__global__ __launch_bounds__(256, 2) void gemm2_kernel(const bf16* __restrict__ act,
                                                       const bf16* __restrict__ W2b,
                                                       float* __restrict__ out,
                                                       const int* __restrict__ counts,
                                                       const int* __restrict__ offsets,
                                                       const int* __restrict__ map,
                                                       const float* __restrict__ wbuf) {
  const int e = blockIdx.z;
  const int n_e = counts[e];
  const int mt = blockIdx.y;
  if (mt * 128 >= n_e) return;
  const int seg = offsets[e];
  const int rmax = n_e - mt * 128;
  const int n0 = blockIdx.x * 128;

  __shared__ __align__(16) bf16 As[128 * 32];
  __shared__ __align__(16) bf16 Bs[128 * 32];
  __shared__ int   smap[128];
  __shared__ float sw[128];

  const int t = threadIdx.x;
  if (t < 128) {
    int rr = t; if (rr > rmax - 1) rr = rmax - 1;
    smap[t] = map[seg + mt * 128 + rr];
    sw[t]   = wbuf[seg + mt * 128 + rr];
  }

  const int r0 = t >> 2;
  const int kq = (t & 3) ^ ((t >> 3) & 3);    // swizzled 16B chunk for staging
  const int lane = t & 63;
  const int w = t >> 6;
  const int wm = w >> 1, wn = w & 1;
  const int quad = lane >> 4, l16 = lane & 15;
  const int wbase = w << 9;

  int ra0 = r0;      if (ra0 > rmax - 1) ra0 = rmax - 1;
  int ra1 = r0 + 64; if (ra1 > rmax - 1) ra1 = rmax - 1;
  const bf16* gA0 = act + (size_t)(seg + mt * 128 + ra0) * F_DIM + (kq << 3);
  const bf16* gA1 = act + (size_t)(seg + mt * 128 + ra1) * F_DIM + (kq << 3);
  const bf16* W2e = W2b + (size_t)e * D_DIM * (size_t)F_DIM;
  const bf16* gB0 = W2e + (size_t)(n0 + r0) * F_DIM + (kq << 3);
  const bf16* gB1 = W2e + (size_t)(n0 + r0 + 64) * F_DIM + (kq << 3);

  f32x4 acc[4][4];
#pragma unroll
  for (int i = 0; i < 4; ++i)
#pragma unroll
    for (int j = 0; j < 4; ++j) acc[i][j] = f32x4{0.f, 0.f, 0.f, 0.f};

  for (int kt = 0; kt < F_DIM / 32; ++kt) {
    g2l16(gA0, As + wbase);
    g2l16(gA1, As + 2048 + wbase);
    g2l16(gB0, Bs + wbase);
    g2l16(gB1, Bs + 2048 + wbase);
    __syncthreads();

    bf16x8 af[4], bf[4];
#pragma unroll
    for (int mi = 0; mi < 4; ++mi)
      af[mi] = *(const bf16x8*)(As + SLOT_OFF(wm * 64 + mi * 16 + l16, quad));
#pragma unroll
    for (int ni = 0; ni < 4; ++ni)
      bf[ni] = *(const bf16x8*)(Bs + SLOT_OFF(wn * 64 + ni * 16 + l16, quad));
#pragma unroll
    for (int mi = 0; mi < 4; ++mi)
#pragma unroll
      for (int ni = 0; ni < 4; ++ni)
        acc[mi][ni] = __builtin_amdgcn_mfma_f32_16x16x32_bf16(af[mi], bf[ni], acc[mi][ni], 0, 0, 0);
    __syncthreads();
    gA0 += 32; gA1 += 32; gB0 += 32; gB1 += 32;
  }

#pragma unroll
  for (int mi = 0; mi < 4; ++mi) {
#pragma unroll
    for (int j = 0; j < 4; ++j) {
      int r = wm * 64 + mi * 16 + quad * 4 + j;
      if (r < rmax) {
        int tok = smap[r];
        float wgt = sw[r];
        float* dst = out + (size_t)tok * D_DIM + n0 + wn * 64 + l16;
#pragma unroll
        for (int ni = 0; ni < 4; ++ni)
          atomicAdd(dst + ni * 16, wgt * acc[mi][ni][j]);
      }
    }
  }
}

// ---------------- launch ----------------

extern "C" void kernel_launch(void* const* d_in, const int* in_sizes, int n_in,
                              void* d_out, int out_size, void* d_ws, size_t ws_size,
                              hipStream_t stream) {
  const float* x   = (const float*)d_in[0];
  const float* gw  = (const float*)d_in[1];
  const float* wv1 = (const float*)d_in[2];
  const float* w2  = (const float*)d_in[3];
  float* out = (float*)d_out;

  const size_t WV1_N = (size_t)E_NUM * 2 * F_DIM * D_DIM;  // 117,440,512
  const size_t W2_N  = (size_t)E_NUM * D_DIM * F_DIM;      //  58,720,256

  char* ws = (char*)d_ws;
  size_t off = 0;
  auto alloc = [&](size_t bytes) -> char* {
    char* p = ws + off;
    off += (bytes + 255) & ~(size_t)255;
    return p;
  };
  bf16*  wv1b   = (bf16*)alloc(WV1_N * 2);
  bf16*  w2b    = (bf16*)alloc(W2_N * 2);
  bf16*  Xg     = (bf16*)alloc((size_t)RTOT * D_DIM * 2);
  bf16*  act    = (bf16*)alloc((size_t)RTOT * F_DIM * 2);
  int*   tok_e  = (int*)alloc(RTOT * 4);
  float* tok_w  = (float*)alloc(RTOT * 4);
  int*   map    = (int*)alloc(RTOT * 4);
  float* wbuf   = (float*)alloc(RTOT * 4);
  int*   counts = (int*)alloc(256);
  int*   offs   = (int*)alloc(256);
  int*   fill   = (int*)alloc(256);
  if (off > ws_size) return;  // workspace too small; fail loudly via wrong output

  zero_f32_kernel<<<2048, 256, 0, stream>>>(out, (size_t)out_size / 4);
  zero_meta_kernel<<<1, 64, 0, stream>>>(counts, fill);
  cvt_bf16_kernel<<<4096, 256, 0, stream>>>(wv1, wv1b, WV1_N);
  cvt_bf16_kernel<<<4096, 256, 0, stream>>>(w2, w2b, W2_N);
  router_kernel<<<T_TOK / 4, 256, 0, stream>>>(x, gw, tok_e, tok_w);
  count_kernel<<<T_TOK / 256, 256, 0, stream>>>(tok_e, counts);
  scan_kernel<<<1, 64, 0, stream>>>(counts, offs, fill);
  scatter_kernel<<<T_TOK / 256, 256, 0, stream>>>(tok_e, tok_w, offs, fill, map, wbuf);
  gather_kernel<<<RTOT, 256, 0, stream>>>(x, map, Xg);
  gemm1_kernel<<<dim3(F_DIM / 128, 64, E_NUM), 256, 0, stream>>>(Xg, wv1b, act, counts, offs);
  gemm2_kernel<<<dim3(D_DIM / 128, 64, E_NUM), 256, 0, stream>>>(act, w2b, out, counts, offs, map, wbuf);
}